// Round 6
// baseline (66.847 us; speedup 1.0000x reference)
//
#include <hip/hip_runtime.h>
#include <math.h>

#define BS 32
#define NA 8400
#define NM 64
#define NC 80
#define BA (BS*NA)          // 268800 anchors total
#define MAXFG 20480         // hard cap: <=10 claims per gt * 2048 gts

// ---- CIoU exactly mirroring the reference (b1 = gt, b2 = pred), clipped at 0
__device__ __forceinline__ float ciou_clip(float g0,float g1,float g2,float g3,
                                           float p0,float p1,float p2,float p3){
    const float eps = 1e-7f;
    float w1 = g2-g0, h1 = (g3-g1)+eps;
    float w2 = p2-p0, h2 = (p3-p1)+eps;
    float iw = fminf(g2,p2)-fmaxf(g0,p0);
    float ih = fminf(g3,p3)-fmaxf(g1,p1);
    float inter = fmaxf(iw,0.f)*fmaxf(ih,0.f);
    float uni = w1*h1 + w2*h2 - inter + eps;
    float iou = inter/uni;
    float cw = fmaxf(g2,p2)-fminf(g0,p0);
    float ch = fmaxf(g3,p3)-fminf(g1,p1);
    float c2 = cw*cw + ch*ch + eps;
    float dx = p0+p2-g0-g2;
    float dy = p1+p3-g1-g3;
    float rho2 = (dx*dx + dy*dy)*0.25f;
    float dat = atanf(w2/h2) - atanf(w1/h1);
    float v = 0.40528473f * (dat*dat);     // 4/pi^2
    float alpha = v/((v - iou) + (1.f + eps));
    float c = iou - (rho2/c2 + v*alpha);
    return fmaxf(c, 0.f);
}

// ---- pass 0: write ALL outputs to their background defaults (coalesced float4
// streams) + init workspace. Background anchor (fg=0): label=gt_labels[b,0],
// bbox=gt_bboxes[b,0], idx=0, fg=0, scores row = 0. ~96 MB pure writes.
__global__ __launch_bounds__(256) void k_zero(
    float* __restrict__ out, int* __restrict__ claim_count, int* __restrict__ claim_min,
    unsigned* __restrict__ pos_align, unsigned* __restrict__ pos_ov,
    int* __restrict__ fg_counter,
    const int* __restrict__ gt_labels, const float* __restrict__ gt_bboxes)
{
    int tid = blockIdx.x*256 + threadIdx.x;
    int stride = gridDim.x*256;
    const float4 z4 = make_float4(0.f,0.f,0.f,0.f);
    // target_scores: 86 MB of zeros
    float4* s4 = (float4*)(out + (size_t)BA*5);
    for (int e = tid; e < BA*20; e += stride) s4[e] = z4;
    // target_bboxes: gt_bboxes[b,0] broadcast
    float4* b4 = (float4*)(out + (size_t)BA);
    for (int e = tid; e < BA; e += stride){
        int b = e / NA;
        b4[e] = *(const float4*)&gt_bboxes[(size_t)b*NM*4];
    }
    // target_labels: gt_labels[b,0] broadcast
    float4* l4 = (float4*)out;
    for (int e = tid; e < BA/4; e += stride){
        int b = e / (NA/4);
        float v = (float)gt_labels[b*NM];
        l4[e] = make_float4(v,v,v,v);
    }
    // fg_mask + target_gt_idx: both zero (contiguous regions)
    float4* f4 = (float4*)(out + (size_t)BA*85);
    for (int e = tid; e < BA/2; e += stride) f4[e] = z4;
    // claim arrays
    int4* cc = (int4*)claim_count;
    for (int e = tid; e < BA/4; e += stride) cc[e] = make_int4(0,0,0,0);
    const int MI = 0x7fffffff;
    int4* cm = (int4*)claim_min;
    for (int e = tid; e < BA/4; e += stride) cm[e] = make_int4(MI,MI,MI,MI);
    // pos arrays + fg counter
    if (tid < BS*NM){ pos_align[tid] = 0u; pos_ov[tid] = 0u; }
    if (tid == 0) *fg_counter = 0;
}

// ---- pass 1: ONE BLOCK per gt, <=1 candidate per thread. SINGLE-PASS top-10:
// candidate selected iff rank under (metric desc, index asc) < 10. One LDS
// stage + one barrier + one broadcast scan — no shuffle chains, no rounds.
// Zero-fill (P<10): top_k pads with globally-smallest-index zero entries;
// an in-gt zero candidate at idx survives mask_in_gts iff (idx - np) < 10-P,
// np = #positives with smaller anchor index (all positives selected when P<10).
__global__ __launch_bounds__(256) void k_topk(
    const float* __restrict__ pd_scores, const float* __restrict__ pd_bboxes,
    const int* __restrict__ gt_labels, const float* __restrict__ gt_bboxes,
    const float* __restrict__ mask_gt,
    int* __restrict__ claim_count, int* __restrict__ claim_min,
    float* __restrict__ claim_align, float* __restrict__ claim_ov)
{
    __shared__ float s_met[256];
    __shared__ int   s_idx[256];
    // XCD swizzle: all 64 gts of one image land on one XCD -> L2 reuse
    int blk  = blockIdx.x;           // 0..2047
    int xcd  = blk & 7;
    int slot = blk >> 3;             // 0..255
    int b = xcd*4 + (slot >> 6);     // 4 images per XCD
    int m = slot & 63;
    if (mask_gt[b*NM + m] <= 0.f) return;   // masked gt -> zero row, no claims

    int t = threadIdx.x;
    float4 g = *(const float4*)&gt_bboxes[(b*NM + m)*4];
    int lab = gt_labels[b*NM + m];
    const float* pb = pd_bboxes + (size_t)b*NA*4;
    const float* ps = pd_scores + (size_t)b*NA*NC + lab;

    // candidate rectangles per level (superset of in-gt anchors; exact dmin filter below)
    const float sinv[3] = {0.125f, 0.0625f, 0.03125f};
    const float sval[3] = {8.f, 16.f, 32.f};
    const int   nlvl[3] = {80, 40, 20};
    const int   aoff[3] = {0, 6400, 8000};
    int xlo[3], xcnt[3], ylo[3], cbase[3];
    int tot = 0;
    #pragma unroll
    for (int l = 0; l < 3; ++l){
        float inv = sinv[l]; int n = nlvl[l];
        int x0 = max(0,   (int)floorf(g.x*inv - 0.5f));
        int x1 = min(n-1, (int)ceilf (g.z*inv - 0.5f));
        int y0 = max(0,   (int)floorf(g.y*inv - 0.5f));
        int y1 = min(n-1, (int)ceilf (g.w*inv - 0.5f));
        xlo[l] = x0; ylo[l] = y0;
        xcnt[l] = max(0, x1-x0+1);
        int yc  = max(0, y1-y0+1);
        cbase[l] = tot;
        tot += xcnt[l]*yc;
    }

    // this thread's candidate (worst case tot ~152 < 256)
    float met = -1.f, ov = 0.f; int aidx = 0x7fffffff;
    bool valid = false;
    if (t < tot){
        int l = (t >= cbase[1]) + (t >= cbase[2]);
        int r = t - cbase[l];
        int cy = r / xcnt[l], cx = r - cy*xcnt[l];
        int gx = xlo[l] + cx, gy = ylo[l] + cy;
        float st = sval[l];
        float ax = (gx + 0.5f)*st, ay = (gy + 0.5f)*st;
        float dmin = fminf(fminf(ax-g.x, ay-g.y), fminf(g.z-ax, g.w-ay));
        if (dmin > 1e-9f){               // exact mask_in_gts
            int a = aoff[l] + gy*nlvl[l] + gx;
            float4 p = *(const float4*)&pb[(size_t)a*4];
            float sc = ps[(size_t)a*NC];     // the scattered HBM gather
            float o = ciou_clip(g.x,g.y,g.z,g.w, p.x,p.y,p.z,p.w);
            met = sc * o; ov = o; aidx = a; valid = true;
        }
    }
    if (t < tot){ s_met[t] = met; s_idx[t] = aidx; }
    __syncthreads();

    if (valid){
        int rank = 0, np = 0, P = 0;
        for (int j = 0; j < tot; ++j){
            float mj = s_met[j]; int ij = s_idx[j];
            bool pos = (mj > 0.f);
            P    += pos;
            rank += (mj > met || (mj == met && ij < aidx));
            np   += (pos && (ij < aidx));
        }
        bool claim;
        if (met > 0.f){
            claim = (rank < 10);
        } else {            // met == 0 candidate: zero-fill slot test
            claim = (P < 10) && ((aidx - np) < (10 - P));
        }
        if (claim){
            atomicAdd(&claim_count[b*NA + aidx], 1);
            atomicMin(&claim_min[b*NA + aidx], m);
            atomicExch(&claim_align[b*NA + aidx], met);
            atomicExch(&claim_ov[b*NA + aidx], ov);   // real ov (matters for pos_overlaps max)
        }
    }
}

// ---- pass 2: claimed anchors only -> resolve gt, pos atomics, append to fg list.
__global__ __launch_bounds__(256) void k_resolve(
    const float* __restrict__ pd_scores, const float* __restrict__ pd_bboxes,
    const int* __restrict__ gt_labels, const float* __restrict__ gt_bboxes,
    const int* __restrict__ claim_count, const int* __restrict__ claim_min,
    const float* __restrict__ claim_align, const float* __restrict__ claim_ov,
    unsigned* __restrict__ pos_align, unsigned* __restrict__ pos_ov,
    int* __restrict__ fg_counter, int4* __restrict__ fglist)
{
    int a = blockIdx.x*256 + threadIdx.x;
    int b = blockIdx.y;
    if (a >= NA) return;
    int i = b*NA + a;
    int cnt = claim_count[i];
    if (cnt == 0) return;                 // background: defaults already written
    int m; float align, ov;
    if (cnt == 1){
        m = claim_min[i];
        align = claim_align[i]; ov = claim_ov[i];
    } else {
        // jnp.argmax over m of clipped overlaps (first max), ALL 64 gts (incl. masked)
        float4 p = *(const float4*)&pd_bboxes[(size_t)i*4];
        float best = -1.f; int bm = 0;
        for (int mm = 0; mm < NM; ++mm){
            float4 g = *(const float4*)&gt_bboxes[(b*NM + mm)*4];
            float o = ciou_clip(g.x,g.y,g.z,g.w, p.x,p.y,p.z,p.w);
            if (o > best){ best = o; bm = mm; }
        }
        m = bm; ov = best;
        int lab = gt_labels[b*NM + m];
        align = pd_scores[(size_t)i*NC + lab] * ov;
    }
    atomicMax(&pos_align[b*NM + m], __float_as_uint(align));  // floats >=0: uint-ordered
    atomicMax(&pos_ov[b*NM + m],    __float_as_uint(ov));
    int slot = atomicAdd(fg_counter, 1);
    fglist[slot] = make_int4(i, m, __float_as_int(align), 0);
}

// ---- pass 3: sparse fixup of fg anchors (<=20480): 5 scalars + 1 score element.
__global__ __launch_bounds__(256) void k_fix(
    const int4* __restrict__ fglist, const int* __restrict__ fg_counter,
    const int* __restrict__ gt_labels, const float* __restrict__ gt_bboxes,
    const unsigned* __restrict__ pos_align, const unsigned* __restrict__ pos_ov,
    float* __restrict__ out)
{
    int t = blockIdx.x*256 + threadIdx.x;
    if (t >= *fg_counter) return;
    int4 e = fglist[t];
    int i = e.x, m = e.y;
    float align = __int_as_float(e.z);
    int b = i / NA;
    float norm = align * __uint_as_float(pos_ov[b*NM + m])
               / (__uint_as_float(pos_align[b*NM + m]) + 1e-9f);
    int lab = gt_labels[b*NM + m];
    out[i] = (float)lab;                                             // target_labels
    *(float4*)&out[(size_t)BA + (size_t)i*4] =
        *(const float4*)&gt_bboxes[(b*NM + m)*4];                    // target_bboxes
    out[(size_t)BA*85 + i] = 1.f;                                    // fg_mask
    out[(size_t)BA*86 + i] = (float)m;                               // target_gt_idx
    out[(size_t)BA*5 + (size_t)i*NC + lab] = norm;                   // one-hot element
}

extern "C" void kernel_launch(void* const* d_in, const int* in_sizes, int n_in,
                              void* d_out, int out_size, void* d_ws, size_t ws_size,
                              hipStream_t stream) {
    const float* pd_scores = (const float*)d_in[0];
    const float* pd_bboxes = (const float*)d_in[1];
    const int*   gt_labels = (const int*)d_in[3];
    const float* gt_bboxes = (const float*)d_in[4];
    const float* mask_gt   = (const float*)d_in[5];
    float* out = (float*)d_out;

    // workspace layout (~4.6 MB; all 16B-aligned: BA*4B = 1,075,200 = 16*67200)
    int*   claim_count = (int*)d_ws;                  // BA
    int*   claim_min   = claim_count + BA;            // BA
    float* claim_align = (float*)(claim_min + BA);    // BA
    float* claim_ov    = claim_align + BA;            // BA
    int4*  fglist      = (int4*)(claim_ov + BA);      // MAXFG int4
    unsigned* pos_align= (unsigned*)(fglist + MAXFG); // BS*NM
    unsigned* pos_ov   = pos_align + BS*NM;           // BS*NM
    int*   fg_counter  = (int*)(pos_ov + BS*NM);      // 1

    k_zero<<<2048, 256, 0, stream>>>(out, claim_count, claim_min,
                                     pos_align, pos_ov, fg_counter,
                                     gt_labels, gt_bboxes);
    k_topk<<<BS*NM, 256, 0, stream>>>(pd_scores, pd_bboxes, gt_labels, gt_bboxes, mask_gt,
                                      claim_count, claim_min, claim_align, claim_ov);
    dim3 gridA((NA + 255)/256, BS);
    k_resolve<<<gridA, 256, 0, stream>>>(pd_scores, pd_bboxes, gt_labels, gt_bboxes,
                                         claim_count, claim_min, claim_align, claim_ov,
                                         pos_align, pos_ov, fg_counter, fglist);
    k_fix<<<MAXFG/256, 256, 0, stream>>>(fglist, fg_counter, gt_labels, gt_bboxes,
                                         pos_align, pos_ov, out);
}

// Round 8
// 36.942 us; speedup vs baseline: 1.8095x; 1.8095x over previous
//
#include <hip/hip_runtime.h>
#include <math.h>

#define BS 32
#define NA 8400
#define NM 64
#define NC 80
#define BA (BS*NA)          // 268800 anchors total
#define KAT 1024            // k_assign block size

typedef float f32x4 __attribute__((ext_vector_type(4)));   // native vector for nontemporal

// ---- CIoU exactly mirroring the reference (b1 = gt, b2 = pred), clipped at 0
__device__ __forceinline__ float ciou_clip(float g0,float g1,float g2,float g3,
                                           float p0,float p1,float p2,float p3){
    const float eps = 1e-7f;
    float w1 = g2-g0, h1 = (g3-g1)+eps;
    float w2 = p2-p0, h2 = (p3-p1)+eps;
    float iw = fminf(g2,p2)-fmaxf(g0,p0);
    float ih = fminf(g3,p3)-fmaxf(g1,p1);
    float inter = fmaxf(iw,0.f)*fmaxf(ih,0.f);
    float uni = w1*h1 + w2*h2 - inter + eps;
    float iou = inter/uni;
    float cw = fmaxf(g2,p2)-fminf(g0,p0);
    float ch = fmaxf(g3,p3)-fminf(g1,p1);
    float c2 = cw*cw + ch*ch + eps;
    float dx = p0+p2-g0-g2;
    float dy = p1+p3-g1-g3;
    float rho2 = (dx*dx + dy*dy)*0.25f;
    float dat = atanf(w2/h2) - atanf(w1/h1);
    float v = 0.40528473f * (dat*dat);     // 4/pi^2
    float alpha = v/((v - iou) + (1.f + eps));
    float c = iou - (rho2/c2 + v*alpha);
    return fmaxf(c, 0.f);
}

// ---- sparse fixup writer (fg anchor): 5 scalars + bbox + one score element
__device__ __forceinline__ void writefix(
    float* __restrict__ out, int b, int a, int m, float align,
    const unsigned* s_pa, const unsigned* s_po,
    const int* __restrict__ gt_labels, const float* __restrict__ gt_bboxes)
{
    size_t i = (size_t)b*NA + a;
    float norm = align * __uint_as_float(s_po[m])
               / (__uint_as_float(s_pa[m]) + 1e-9f);
    int lab = gt_labels[b*NM + m];
    out[i] = (float)lab;                                             // target_labels
    *(float4*)&out[(size_t)BA + i*4] =
        *(const float4*)&gt_bboxes[(b*NM + m)*4];                    // target_bboxes
    out[(size_t)BA*85 + i] = 1.f;                                    // fg_mask
    out[(size_t)BA*86 + i] = (float)m;                               // target_gt_idx
    out[(size_t)BA*5 + i*NC + lab] = norm;                           // one-hot element
}

// ---- pass 0: ONLY the 93.5 MB output-default write (no ws init needed at all).
// Background anchor: label=gt_labels[b,0], bbox=gt_bboxes[b,0], idx=0, fg=0, scores=0.
__global__ __launch_bounds__(256) void k_zero(
    float* __restrict__ out,
    const int* __restrict__ gt_labels, const float* __restrict__ gt_bboxes)
{
    int tid = blockIdx.x*256 + threadIdx.x;
    int stride = gridDim.x*256;
    const f32x4 z4 = (f32x4){0.f,0.f,0.f,0.f};
    // target_scores: 86 MB of zeros, nontemporal (pure streaming, no reuse)
    f32x4* s4 = (f32x4*)(out + (size_t)BA*5);
    for (int e = tid; e < BA*20; e += stride)
        __builtin_nontemporal_store(z4, &s4[e]);
    // target_bboxes: gt_bboxes[b,0] broadcast
    float4* b4 = (float4*)(out + (size_t)BA);
    for (int e = tid; e < BA; e += stride){
        int b = e / NA;
        b4[e] = *(const float4*)&gt_bboxes[(size_t)b*NM*4];
    }
    // target_labels: gt_labels[b,0] broadcast
    float4* l4 = (float4*)out;
    for (int e = tid; e < BA/4; e += stride){
        int b = e / (NA/4);
        float v = (float)gt_labels[b*NM];
        l4[e] = make_float4(v,v,v,v);
    }
    // fg_mask + target_gt_idx: contiguous 2*BA floats of zero
    f32x4* f4 = (f32x4*)(out + (size_t)BA*85);
    for (int e = tid; e < BA/2; e += stride)
        __builtin_nontemporal_store(z4, &f4[e]);
}

// ---- pass 1: ONE BLOCK per gt, <=1 candidate per thread, single-pass rank
// selection (exact jax.lax.top_k semantics, 5 rounds bit-exact).
// Claims go to a DENSE per-gt list via an LDS slot counter — no global
// atomics, no workspace init dependency.
__global__ __launch_bounds__(256) void k_topk(
    const float* __restrict__ pd_scores, const float* __restrict__ pd_bboxes,
    const int* __restrict__ gt_labels, const float* __restrict__ gt_bboxes,
    const float* __restrict__ mask_gt,
    int4* __restrict__ sel, int* __restrict__ sel_cnt)
{
    __shared__ float s_met[256];
    __shared__ int   s_idx[256];
    __shared__ unsigned s_nsel;
    // XCD swizzle: all 64 gts of one image land on one XCD -> L2 reuse
    int blk  = blockIdx.x;           // 0..2047
    int xcd  = blk & 7;
    int slot = blk >> 3;             // 0..255
    int b = xcd*4 + (slot >> 6);     // 4 images per XCD
    int m = slot & 63;
    int gt = b*NM + m;
    int t = threadIdx.x;
    if (mask_gt[gt] <= 0.f){         // masked gt -> empty list (written every call)
        if (t == 0) sel_cnt[gt] = 0;
        return;
    }
    if (t == 0) s_nsel = 0u;

    float4 g = *(const float4*)&gt_bboxes[(size_t)gt*4];
    int lab = gt_labels[gt];
    const float* pb = pd_bboxes + (size_t)b*NA*4;
    const float* ps = pd_scores + (size_t)b*NA*NC + lab;

    // candidate rectangles per level (superset of in-gt anchors; exact dmin filter below)
    const float sinv[3] = {0.125f, 0.0625f, 0.03125f};
    const float sval[3] = {8.f, 16.f, 32.f};
    const int   nlvl[3] = {80, 40, 20};
    const int   aoff[3] = {0, 6400, 8000};
    int xlo[3], xcnt[3], ylo[3], cbase[3];
    int tot = 0;
    #pragma unroll
    for (int l = 0; l < 3; ++l){
        float inv = sinv[l]; int n = nlvl[l];
        int x0 = max(0,   (int)floorf(g.x*inv - 0.5f));
        int x1 = min(n-1, (int)ceilf (g.z*inv - 0.5f));
        int y0 = max(0,   (int)floorf(g.y*inv - 0.5f));
        int y1 = min(n-1, (int)ceilf (g.w*inv - 0.5f));
        xlo[l] = x0; ylo[l] = y0;
        xcnt[l] = max(0, x1-x0+1);
        int yc  = max(0, y1-y0+1);
        cbase[l] = tot;
        tot += xcnt[l]*yc;
    }

    // this thread's candidate (worst case tot ~152 < 256)
    float met = -1.f, ov = 0.f; int aidx = 0x7fffffff;
    bool valid = false;
    if (t < tot){
        int l = (t >= cbase[1]) + (t >= cbase[2]);
        int r = t - cbase[l];
        int cy = r / xcnt[l], cx = r - cy*xcnt[l];
        int gx = xlo[l] + cx, gy = ylo[l] + cy;
        float st = sval[l];
        float ax = (gx + 0.5f)*st, ay = (gy + 0.5f)*st;
        float dmin = fminf(fminf(ax-g.x, ay-g.y), fminf(g.z-ax, g.w-ay));
        if (dmin > 1e-9f){               // exact mask_in_gts
            int a = aoff[l] + gy*nlvl[l] + gx;
            float4 p = *(const float4*)&pb[(size_t)a*4];
            float sc = ps[(size_t)a*NC];     // the scattered HBM gather
            float o = ciou_clip(g.x,g.y,g.z,g.w, p.x,p.y,p.z,p.w);
            met = sc * o; ov = o; aidx = a; valid = true;
        }
    }
    if (t < tot){ s_met[t] = met; s_idx[t] = aidx; }
    __syncthreads();

    if (valid){
        int rank = 0, np = 0, P = 0;
        for (int j = 0; j < tot; ++j){
            float mj = s_met[j]; int ij = s_idx[j];
            bool pos = (mj > 0.f);
            P    += pos;
            rank += (mj > met || (mj == met && ij < aidx));
            np   += (pos && (ij < aidx));
        }
        bool claim;
        if (met > 0.f){
            claim = (rank < 10);
        } else {            // met == 0 candidate: zero-fill slot test
            claim = (P < 10) && ((aidx - np) < (10 - P));
        }
        if (claim){          // <=10 claims -> 16-slot stride is safe
            unsigned sl = atomicAdd(&s_nsel, 1u);
            sel[((size_t)gt<<4) + sl] =
                make_int4(aidx, __float_as_int(met), __float_as_int(ov), 0);
        }
    }
    __syncthreads();
    if (t == 0) sel_cnt[gt] = (int)s_nsel;
}

// ---- pass 2: ONE BLOCK PER IMAGE. Stage <=640 claims, count/min per anchor in
// LDS, resolve multi-claim anchors one-wave-per-anchor, pos maxima in LDS,
// write all sparse fixups. Replaces dense resolve + fix kernels.
__global__ __launch_bounds__(KAT) void k_assign(
    const float* __restrict__ pd_scores, const float* __restrict__ pd_bboxes,
    const int* __restrict__ gt_labels, const float* __restrict__ gt_bboxes,
    const int4* __restrict__ sel, const int* __restrict__ sel_cnt,
    float* __restrict__ out)
{
    __shared__ unsigned s_cnt[NA];       // claim count per anchor (33.6 KB)
    __shared__ unsigned s_min[NA];       // min claiming gt per anchor (33.6 KB)
    __shared__ unsigned s_pa[NM], s_po[NM];   // pos_align / pos_overlaps (uint max)
    __shared__ int  s_mn;
    __shared__ int4 s_multi[320];        // {a, m*, align_bits, done}; cap 640/2
    int b = blockIdx.x;
    int t = threadIdx.x;

    for (int j = t; j < NA; j += KAT){ s_cnt[j] = 0u; s_min[j] = 0xffffffffu; }
    if (t < NM){ s_pa[t] = 0u; s_po[t] = 0u; }
    if (t == 0) s_mn = 0;
    __syncthreads();

    // phase 1: load this thread's claim entry (64 gts x 16 slots == 1024 threads)
    int gt = t >> 4, slotn = t & 15;
    bool has = false; int a = 0; float met = 0.f, ov = 0.f;
    if (slotn < sel_cnt[b*NM + gt]){
        int4 e = sel[((size_t)(b*NM + gt) << 4) + slotn];
        a = e.x; met = __int_as_float(e.y); ov = __int_as_float(e.z);
        has = true;
        atomicAdd(&s_cnt[a], 1u);
        atomicMin(&s_min[a], (unsigned)gt);
    }
    __syncthreads();

    // phase 2a: single-claim anchors -> pos maxima; multi-claim -> dedup'd list
    unsigned c = 0;
    if (has){
        c = s_cnt[a];
        if (c == 1u){
            atomicMax(&s_pa[gt], __float_as_uint(met));
            atomicMax(&s_po[gt], __float_as_uint(ov));
        } else if (s_min[a] == (unsigned)gt){   // exactly one entry per multi anchor
            int k = atomicAdd(&s_mn, 1);
            s_multi[k] = make_int4(a, 0, 0, 0);
        }
    }
    __syncthreads();

    // phase 2b: one wave per multi anchor; lane mm = gt mm (jnp.argmax: first max)
    int wv = t >> 6, lane = t & 63;
    for (int k = wv; k < s_mn; k += KAT/64){
        int aa = s_multi[k].x;
        float4 p = *(const float4*)&pd_bboxes[((size_t)b*NA + aa)*4]; // broadcast
        float4 g = *(const float4*)&gt_bboxes[(b*NM + lane)*4];
        float o = ciou_clip(g.x,g.y,g.z,g.w, p.x,p.y,p.z,p.w);
        float bv = o; int bi = lane;
        #pragma unroll
        for (int d = 1; d < 64; d <<= 1){
            float o2 = __shfl_xor(bv, d);
            int   i2 = __shfl_xor(bi, d);
            if (o2 > bv || (o2 == bv && i2 < bi)){ bv = o2; bi = i2; }
        }
        if (lane == bi){                 // unique winner lane
            int lab = gt_labels[b*NM + bi];
            float al = pd_scores[((size_t)b*NA + aa)*NC + lab] * bv;
            atomicMax(&s_pa[bi], __float_as_uint(al));
            atomicMax(&s_po[bi], __float_as_uint(bv));
            s_multi[k] = make_int4(aa, bi, __float_as_int(al), 1);
        }
    }
    __syncthreads();

    // phase 3: pos arrays final -> write all fg fixups
    if (has && c == 1u)
        writefix(out, b, a, gt, met, s_pa, s_po, gt_labels, gt_bboxes);
    if (t < s_mn){
        int4 mm = s_multi[t];
        writefix(out, b, mm.x, mm.y, __int_as_float(mm.z), s_pa, s_po,
                 gt_labels, gt_bboxes);
    }
}

extern "C" void kernel_launch(void* const* d_in, const int* in_sizes, int n_in,
                              void* d_out, int out_size, void* d_ws, size_t ws_size,
                              hipStream_t stream) {
    const float* pd_scores = (const float*)d_in[0];
    const float* pd_bboxes = (const float*)d_in[1];
    const int*   gt_labels = (const int*)d_in[3];
    const float* gt_bboxes = (const float*)d_in[4];
    const float* mask_gt   = (const float*)d_in[5];
    float* out = (float*)d_out;

    // workspace: dense per-gt claim lists only (~520 KB, fully written each call)
    int4* sel     = (int4*)d_ws;                 // 2048 * 16 int4
    int*  sel_cnt = (int*)(sel + (size_t)BS*NM*16);  // 2048

    k_zero<<<2048, 256, 0, stream>>>(out, gt_labels, gt_bboxes);
    k_topk<<<BS*NM, 256, 0, stream>>>(pd_scores, pd_bboxes, gt_labels, gt_bboxes,
                                      mask_gt, sel, sel_cnt);
    k_assign<<<BS, KAT, 0, stream>>>(pd_scores, pd_bboxes, gt_labels, gt_bboxes,
                                     sel, sel_cnt, out);
}

// Round 9
// 32.767 us; speedup vs baseline: 2.0401x; 1.1274x over previous
//
#include <hip/hip_runtime.h>
#include <math.h>

#define BS 32
#define NA 8400
#define NM 64
#define NC 80
#define BA (BS*NA)          // 268800 anchors total
#define KAT 1024            // k_assign block size

typedef float f32x4 __attribute__((ext_vector_type(4)));   // native vector for nontemporal

// ---- CIoU exactly mirroring the reference (b1 = gt, b2 = pred), clipped at 0
__device__ __forceinline__ float ciou_clip(float g0,float g1,float g2,float g3,
                                           float p0,float p1,float p2,float p3){
    const float eps = 1e-7f;
    float w1 = g2-g0, h1 = (g3-g1)+eps;
    float w2 = p2-p0, h2 = (p3-p1)+eps;
    float iw = fminf(g2,p2)-fmaxf(g0,p0);
    float ih = fminf(g3,p3)-fmaxf(g1,p1);
    float inter = fmaxf(iw,0.f)*fmaxf(ih,0.f);
    float uni = w1*h1 + w2*h2 - inter + eps;
    float iou = inter/uni;
    float cw = fmaxf(g2,p2)-fminf(g0,p0);
    float ch = fmaxf(g3,p3)-fminf(g1,p1);
    float c2 = cw*cw + ch*ch + eps;
    float dx = p0+p2-g0-g2;
    float dy = p1+p3-g1-g3;
    float rho2 = (dx*dx + dy*dy)*0.25f;
    float dat = atanf(w2/h2) - atanf(w1/h1);
    float v = 0.40528473f * (dat*dat);     // 4/pi^2
    float alpha = v/((v - iou) + (1.f + eps));
    float c = iou - (rho2/c2 + v*alpha);
    return fmaxf(c, 0.f);
}

// ---- sparse fixup writer (fg anchor): 5 scalars + bbox + one score element
__device__ __forceinline__ void writefix(
    float* __restrict__ out, int b, int a, int m, float align,
    const unsigned* s_pa, const unsigned* s_po,
    const int* __restrict__ gt_labels, const float* __restrict__ gt_bboxes)
{
    size_t i = (size_t)b*NA + a;
    float norm = align * __uint_as_float(s_po[m])
               / (__uint_as_float(s_pa[m]) + 1e-9f);
    int lab = gt_labels[b*NM + m];
    out[i] = (float)lab;                                             // target_labels
    *(float4*)&out[(size_t)BA + i*4] =
        *(const float4*)&gt_bboxes[(b*NM + m)*4];                    // target_bboxes
    out[(size_t)BA*85 + i] = 1.f;                                    // fg_mask
    out[(size_t)BA*86 + i] = (float)m;                               // target_gt_idx
    out[(size_t)BA*5 + i*NC + lab] = norm;                           // one-hot element
}

// ---- pass 1 (fused): per-block = top-10 for ONE gt  +  a stripe of the 93.5 MB
// output-default write. The gt's scattered gathers are issued FIRST (loads into
// registers), the streaming stores run while they're in flight, then the rank
// scan + claim-list writes. Gather latency hides under the store stream.
__global__ __launch_bounds__(256) void k_main(
    const float* __restrict__ pd_scores, const float* __restrict__ pd_bboxes,
    const int* __restrict__ gt_labels, const float* __restrict__ gt_bboxes,
    const float* __restrict__ mask_gt,
    int4* __restrict__ sel, int* __restrict__ sel_cnt,
    float* __restrict__ out)
{
    __shared__ float s_met[256];
    __shared__ int   s_idx[256];
    __shared__ unsigned s_nsel;
    // XCD swizzle: all 64 gts of one image land on one XCD -> L2 reuse
    int blk  = blockIdx.x;           // 0..2047
    int xcd  = blk & 7;
    int slot = blk >> 3;             // 0..255
    int b = xcd*4 + (slot >> 6);     // 4 images per XCD
    int m = slot & 63;
    int gt = b*NM + m;
    int t = threadIdx.x;
    bool active = (mask_gt[gt] > 0.f);
    if (t == 0){ s_nsel = 0u; }

    // ---- gt candidate setup + ISSUE the scattered loads (registers p4, sc)
    float4 g; int lab = 0;
    float4 p4 = make_float4(0.f,0.f,0.f,0.f);
    float sc = 0.f;
    float ax = 0.f, ay = 0.f;
    int aidx = 0x7fffffff;
    bool inGt = false;
    int tot = 0;
    if (active){
        g = *(const float4*)&gt_bboxes[(size_t)gt*4];
        lab = gt_labels[gt];
        const float* pb = pd_bboxes + (size_t)b*NA*4;
        const float* ps = pd_scores + (size_t)b*NA*NC + lab;
        const float sinv[3] = {0.125f, 0.0625f, 0.03125f};
        const float sval[3] = {8.f, 16.f, 32.f};
        const int   nlvl[3] = {80, 40, 20};
        const int   aoff[3] = {0, 6400, 8000};
        int xlo[3], xcnt[3], ylo[3], cbase[3];
        #pragma unroll
        for (int l = 0; l < 3; ++l){
            float inv = sinv[l]; int n = nlvl[l];
            int x0 = max(0,   (int)floorf(g.x*inv - 0.5f));
            int x1 = min(n-1, (int)ceilf (g.z*inv - 0.5f));
            int y0 = max(0,   (int)floorf(g.y*inv - 0.5f));
            int y1 = min(n-1, (int)ceilf (g.w*inv - 0.5f));
            xlo[l] = x0; ylo[l] = y0;
            xcnt[l] = max(0, x1-x0+1);
            int yc  = max(0, y1-y0+1);
            cbase[l] = tot;
            tot += xcnt[l]*yc;
        }
        if (t < tot){
            int l = (t >= cbase[1]) + (t >= cbase[2]);
            int r = t - cbase[l];
            int cy = r / xcnt[l], cx = r - cy*xcnt[l];
            int gx = xlo[l] + cx, gy = ylo[l] + cy;
            float st = sval[l];
            ax = (gx + 0.5f)*st; ay = (gy + 0.5f)*st;
            float dmin = fminf(fminf(ax-g.x, ay-g.y), fminf(g.z-ax, g.w-ay));
            if (dmin > 1e-9f){           // exact mask_in_gts
                int a = aoff[l] + gy*nlvl[l] + gx;
                p4 = *(const float4*)&pb[(size_t)a*4];    // issued here...
                sc = ps[(size_t)a*NC];                    // ...latency hidden below
                aidx = a; inGt = true;
            }
        }
    }

    // ---- zero-fill stripe (write-BW stream; overlaps the gathers above)
    {
        int tid = blk*256 + t;
        const int stride = 2048*256;
        const f32x4 z4 = (f32x4){0.f,0.f,0.f,0.f};
        f32x4* s4 = (f32x4*)(out + (size_t)BA*5);        // target_scores: 86 MB
        for (int e = tid; e < BA*20; e += stride)
            __builtin_nontemporal_store(z4, &s4[e]);
        float4* b4 = (float4*)(out + (size_t)BA);        // target_bboxes: gt[b,0]
        for (int e = tid; e < BA; e += stride){
            int bb = e / NA;
            b4[e] = *(const float4*)&gt_bboxes[(size_t)bb*NM*4];
        }
        float4* l4 = (float4*)out;                        // target_labels: gt_labels[b,0]
        for (int e = tid; e < BA/4; e += stride){
            int bb = e / (NA/4);
            float v = (float)gt_labels[bb*NM];
            l4[e] = make_float4(v,v,v,v);
        }
        f32x4* f4 = (f32x4*)(out + (size_t)BA*85);       // fg_mask + gt_idx: zeros
        for (int e = tid; e < BA/2; e += stride)
            __builtin_nontemporal_store(z4, &f4[e]);
    }

    // ---- metric + single-pass rank selection (exact jax.lax.top_k semantics)
    if (!active){
        if (t == 0) sel_cnt[gt] = 0;
        return;
    }
    float met = -1.f, ov = 0.f;
    if (inGt){
        float o = ciou_clip(g.x,g.y,g.z,g.w, p4.x,p4.y,p4.z,p4.w);
        met = sc * o; ov = o;
    }
    if (t < tot){ s_met[t] = met; s_idx[t] = aidx; }
    __syncthreads();

    if (inGt){
        int rank = 0, np = 0, P = 0;
        for (int j = 0; j < tot; ++j){
            float mj = s_met[j]; int ij = s_idx[j];
            bool pos = (mj > 0.f);
            P    += pos;
            rank += (mj > met || (mj == met && ij < aidx));
            np   += (pos && (ij < aidx));
        }
        bool claim;
        if (met > 0.f){
            claim = (rank < 10);
        } else {            // met == 0 candidate: zero-fill slot test
            claim = (P < 10) && ((aidx - np) < (10 - P));
        }
        if (claim){          // <=10 claims -> 16-slot stride is safe
            unsigned sl = atomicAdd(&s_nsel, 1u);
            sel[((size_t)gt<<4) + sl] =
                make_int4(aidx, __float_as_int(met), __float_as_int(ov), 0);
        }
    }
    __syncthreads();
    if (t == 0) sel_cnt[gt] = (int)s_nsel;
}

// ---- pass 2: ONE BLOCK PER IMAGE. Stage <=640 claims, count/min per anchor in
// LDS, resolve multi-claim anchors one-wave-per-anchor, pos maxima in LDS,
// write all sparse fixups.
__global__ __launch_bounds__(KAT) void k_assign(
    const float* __restrict__ pd_scores, const float* __restrict__ pd_bboxes,
    const int* __restrict__ gt_labels, const float* __restrict__ gt_bboxes,
    const int4* __restrict__ sel, const int* __restrict__ sel_cnt,
    float* __restrict__ out)
{
    __shared__ unsigned s_cnt[NA];       // claim count per anchor (33.6 KB)
    __shared__ unsigned s_min[NA];       // min claiming gt per anchor (33.6 KB)
    __shared__ unsigned s_pa[NM], s_po[NM];   // pos_align / pos_overlaps (uint max)
    __shared__ int  s_mn;
    __shared__ int4 s_multi[320];        // {a, m*, align_bits, done}; cap 640/2
    int b = blockIdx.x;
    int t = threadIdx.x;

    for (int j = t; j < NA; j += KAT){ s_cnt[j] = 0u; s_min[j] = 0xffffffffu; }
    if (t < NM){ s_pa[t] = 0u; s_po[t] = 0u; }
    if (t == 0) s_mn = 0;
    __syncthreads();

    // phase 1: load this thread's claim entry (64 gts x 16 slots == 1024 threads)
    int gt = t >> 4, slotn = t & 15;
    bool has = false; int a = 0; float met = 0.f, ov = 0.f;
    if (slotn < sel_cnt[b*NM + gt]){
        int4 e = sel[((size_t)(b*NM + gt) << 4) + slotn];
        a = e.x; met = __int_as_float(e.y); ov = __int_as_float(e.z);
        has = true;
        atomicAdd(&s_cnt[a], 1u);
        atomicMin(&s_min[a], (unsigned)gt);
    }
    __syncthreads();

    // phase 2a: single-claim anchors -> pos maxima; multi-claim -> dedup'd list
    unsigned c = 0;
    if (has){
        c = s_cnt[a];
        if (c == 1u){
            atomicMax(&s_pa[gt], __float_as_uint(met));
            atomicMax(&s_po[gt], __float_as_uint(ov));
        } else if (s_min[a] == (unsigned)gt){   // exactly one entry per multi anchor
            int k = atomicAdd(&s_mn, 1);
            s_multi[k] = make_int4(a, 0, 0, 0);
        }
    }
    __syncthreads();

    // phase 2b: one wave per multi anchor; lane mm = gt mm (jnp.argmax: first max)
    int wv = t >> 6, lane = t & 63;
    for (int k = wv; k < s_mn; k += KAT/64){
        int aa = s_multi[k].x;
        float4 p = *(const float4*)&pd_bboxes[((size_t)b*NA + aa)*4]; // broadcast
        float4 g = *(const float4*)&gt_bboxes[(b*NM + lane)*4];
        float o = ciou_clip(g.x,g.y,g.z,g.w, p.x,p.y,p.z,p.w);
        float bv = o; int bi = lane;
        #pragma unroll
        for (int d = 1; d < 64; d <<= 1){
            float o2 = __shfl_xor(bv, d);
            int   i2 = __shfl_xor(bi, d);
            if (o2 > bv || (o2 == bv && i2 < bi)){ bv = o2; bi = i2; }
        }
        if (lane == bi){                 // unique winner lane
            int lab = gt_labels[b*NM + bi];
            float al = pd_scores[((size_t)b*NA + aa)*NC + lab] * bv;
            atomicMax(&s_pa[bi], __float_as_uint(al));
            atomicMax(&s_po[bi], __float_as_uint(bv));
            s_multi[k] = make_int4(aa, bi, __float_as_int(al), 1);
        }
    }
    __syncthreads();

    // phase 3: pos arrays final -> write all fg fixups
    if (has && c == 1u)
        writefix(out, b, a, gt, met, s_pa, s_po, gt_labels, gt_bboxes);
    if (t < s_mn){
        int4 mm = s_multi[t];
        writefix(out, b, mm.x, mm.y, __int_as_float(mm.z), s_pa, s_po,
                 gt_labels, gt_bboxes);
    }
}

extern "C" void kernel_launch(void* const* d_in, const int* in_sizes, int n_in,
                              void* d_out, int out_size, void* d_ws, size_t ws_size,
                              hipStream_t stream) {
    const float* pd_scores = (const float*)d_in[0];
    const float* pd_bboxes = (const float*)d_in[1];
    const int*   gt_labels = (const int*)d_in[3];
    const float* gt_bboxes = (const float*)d_in[4];
    const float* mask_gt   = (const float*)d_in[5];
    float* out = (float*)d_out;

    // workspace: dense per-gt claim lists only (~520 KB, fully written each call)
    int4* sel     = (int4*)d_ws;                 // 2048 * 16 int4
    int*  sel_cnt = (int*)(sel + (size_t)BS*NM*16);  // 2048

    k_main<<<BS*NM, 256, 0, stream>>>(pd_scores, pd_bboxes, gt_labels, gt_bboxes,
                                      mask_gt, sel, sel_cnt, out);
    k_assign<<<BS, KAT, 0, stream>>>(pd_scores, pd_bboxes, gt_labels, gt_bboxes,
                                     sel, sel_cnt, out);
}

// Round 10
// 28.031 us; speedup vs baseline: 2.3847x; 1.1689x over previous
//
#include <hip/hip_runtime.h>
#include <math.h>

#define BS 32
#define NA 8400
#define NM 64
#define NC 80
#define BA (BS*NA)          // 268800 anchors total
#define KAT 1024            // k_assign block size
#define GRID 4096           // k_main grid: 2048 topk blocks + 2048 store-only blocks

// ---- CIoU exactly mirroring the reference (b1 = gt, b2 = pred), clipped at 0
__device__ __forceinline__ float ciou_clip(float g0,float g1,float g2,float g3,
                                           float p0,float p1,float p2,float p3){
    const float eps = 1e-7f;
    float w1 = g2-g0, h1 = (g3-g1)+eps;
    float w2 = p2-p0, h2 = (p3-p1)+eps;
    float iw = fminf(g2,p2)-fmaxf(g0,p0);
    float ih = fminf(g3,p3)-fmaxf(g1,p1);
    float inter = fmaxf(iw,0.f)*fmaxf(ih,0.f);
    float uni = w1*h1 + w2*h2 - inter + eps;
    float iou = inter/uni;
    float cw = fmaxf(g2,p2)-fminf(g0,p0);
    float ch = fmaxf(g3,p3)-fminf(g1,p1);
    float c2 = cw*cw + ch*ch + eps;
    float dx = p0+p2-g0-g2;
    float dy = p1+p3-g1-g3;
    float rho2 = (dx*dx + dy*dy)*0.25f;
    float dat = atanf(w2/h2) - atanf(w1/h1);
    float v = 0.40528473f * (dat*dat);     // 4/pi^2
    float alpha = v/((v - iou) + (1.f + eps));
    float c = iou - (rho2/c2 + v*alpha);
    return fmaxf(c, 0.f);
}

// ---- sparse fixup writer (fg anchor): 5 scalars + bbox + one score element
__device__ __forceinline__ void writefix(
    float* __restrict__ out, int b, int a, int m, float align,
    const unsigned* s_pa, const unsigned* s_po,
    const int* __restrict__ gt_labels, const float* __restrict__ gt_bboxes)
{
    size_t i = (size_t)b*NA + a;
    float norm = align * __uint_as_float(s_po[m])
               / (__uint_as_float(s_pa[m]) + 1e-9f);
    int lab = gt_labels[b*NM + m];
    out[i] = (float)lab;                                             // target_labels
    *(float4*)&out[(size_t)BA + i*4] =
        *(const float4*)&gt_bboxes[(b*NM + m)*4];                    // target_bboxes
    out[(size_t)BA*85 + i] = 1.f;                                    // fg_mask
    out[(size_t)BA*86 + i] = (float)m;                               // target_gt_idx
    out[(size_t)BA*5 + i*NC + lab] = norm;                           // one-hot element
}

// ---- pass 1 (fused): blocks 0..2047 = top-10 for one gt + a store stripe;
// blocks 2048..4095 = pure store stripes. Plain (cached) float4 stores — the
// harness fill sustains 6.85 TB/s with this path; nontemporal measured slower.
__global__ __launch_bounds__(256) void k_main(
    const float* __restrict__ pd_scores, const float* __restrict__ pd_bboxes,
    const int* __restrict__ gt_labels, const float* __restrict__ gt_bboxes,
    const float* __restrict__ mask_gt,
    int4* __restrict__ sel, int* __restrict__ sel_cnt,
    float* __restrict__ out)
{
    __shared__ float s_met[256];
    __shared__ int   s_idx[256];
    __shared__ unsigned s_nsel;
    int blk  = blockIdx.x;
    int t = threadIdx.x;
    bool topk_blk = (blk < BS*NM);

    // XCD swizzle (topk blocks): all 64 gts of one image land on one XCD
    int b = 0, m = 0, gt = 0;
    bool active = false;
    if (topk_blk){
        int xcd  = blk & 7;
        int slot = blk >> 3;             // 0..255
        b = xcd*4 + (slot >> 6);         // 4 images per XCD
        m = slot & 63;
        gt = b*NM + m;
        active = (mask_gt[gt] > 0.f);
        if (t == 0) s_nsel = 0u;
    }

    // ---- gt candidate setup + ISSUE the scattered loads (registers p4, sc)
    float4 g = make_float4(0.f,0.f,0.f,0.f);
    float4 p4 = make_float4(0.f,0.f,0.f,0.f);
    float sc = 0.f;
    int aidx = 0x7fffffff;
    bool inGt = false;
    int tot = 0;
    if (active){
        g = *(const float4*)&gt_bboxes[(size_t)gt*4];
        int lab = gt_labels[gt];
        const float* pb = pd_bboxes + (size_t)b*NA*4;
        const float* ps = pd_scores + (size_t)b*NA*NC + lab;
        const float sinv[3] = {0.125f, 0.0625f, 0.03125f};
        const float sval[3] = {8.f, 16.f, 32.f};
        const int   nlvl[3] = {80, 40, 20};
        const int   aoff[3] = {0, 6400, 8000};
        int xlo[3], xcnt[3], ylo[3], cbase[3];
        #pragma unroll
        for (int l = 0; l < 3; ++l){
            float inv = sinv[l]; int n = nlvl[l];
            int x0 = max(0,   (int)floorf(g.x*inv - 0.5f));
            int x1 = min(n-1, (int)ceilf (g.z*inv - 0.5f));
            int y0 = max(0,   (int)floorf(g.y*inv - 0.5f));
            int y1 = min(n-1, (int)ceilf (g.w*inv - 0.5f));
            xlo[l] = x0; ylo[l] = y0;
            xcnt[l] = max(0, x1-x0+1);
            int yc  = max(0, y1-y0+1);
            cbase[l] = tot;
            tot += xcnt[l]*yc;
        }
        if (t < tot){
            int l = (t >= cbase[1]) + (t >= cbase[2]);
            int r = t - cbase[l];
            int cy = r / xcnt[l], cx = r - cy*xcnt[l];
            int gx = xlo[l] + cx, gy = ylo[l] + cy;
            float st = sval[l];
            float ax = (gx + 0.5f)*st, ay = (gy + 0.5f)*st;
            float dmin = fminf(fminf(ax-g.x, ay-g.y), fminf(g.z-ax, g.w-ay));
            if (dmin > 1e-9f){           // exact mask_in_gts
                int a = aoff[l] + gy*nlvl[l] + gx;
                p4 = *(const float4*)&pb[(size_t)a*4];    // issued here...
                sc = ps[(size_t)a*NC];                    // ...latency hidden below
                aidx = a; inGt = true;
            }
        }
    }

    // ---- zero-fill stripe (write-BW stream; overlaps the gathers above)
    {
        int tid = blk*256 + t;
        const int stride = GRID*256;
        const float4 z4 = make_float4(0.f,0.f,0.f,0.f);
        float4* s4 = (float4*)(out + (size_t)BA*5);      // target_scores: 86 MB
        for (int e = tid; e < BA*20; e += stride)
            s4[e] = z4;
        float4* b4 = (float4*)(out + (size_t)BA);        // target_bboxes: gt[b,0]
        for (int e = tid; e < BA; e += stride){
            int bb = e / NA;
            b4[e] = *(const float4*)&gt_bboxes[(size_t)bb*NM*4];
        }
        float4* l4 = (float4*)out;                        // target_labels: gt_labels[b,0]
        for (int e = tid; e < BA/4; e += stride){
            int bb = e / (NA/4);
            float v = (float)gt_labels[bb*NM];
            l4[e] = make_float4(v,v,v,v);
        }
        float4* f4 = (float4*)(out + (size_t)BA*85);     // fg_mask + gt_idx: zeros
        for (int e = tid; e < BA/2; e += stride)
            f4[e] = z4;
    }

    // ---- metric + single-pass rank selection (exact jax.lax.top_k semantics)
    if (!topk_blk) return;
    if (!active){
        if (t == 0) sel_cnt[gt] = 0;
        return;
    }
    float met = -1.f, ov = 0.f;
    if (inGt){
        float o = ciou_clip(g.x,g.y,g.z,g.w, p4.x,p4.y,p4.z,p4.w);
        met = sc * o; ov = o;
    }
    if (t < tot){ s_met[t] = met; s_idx[t] = aidx; }
    __syncthreads();

    if (inGt){
        int rank = 0, np = 0, P = 0;
        for (int j = 0; j < tot; ++j){
            float mj = s_met[j]; int ij = s_idx[j];
            bool pos = (mj > 0.f);
            P    += pos;
            rank += (mj > met || (mj == met && ij < aidx));
            np   += (pos && (ij < aidx));
        }
        bool claim;
        if (met > 0.f){
            claim = (rank < 10);
        } else {            // met == 0 candidate: zero-fill slot test
            claim = (P < 10) && ((aidx - np) < (10 - P));
        }
        if (claim){          // <=10 claims -> 16-slot stride is safe
            unsigned sl = atomicAdd(&s_nsel, 1u);
            sel[((size_t)gt<<4) + sl] =
                make_int4(aidx, __float_as_int(met), __float_as_int(ov), 0);
        }
    }
    __syncthreads();
    if (t == 0) sel_cnt[gt] = (int)s_nsel;
}

// ---- pass 2: ONE BLOCK PER IMAGE. Stage <=640 claims, count/min per anchor in
// LDS, resolve multi-claim anchors one-wave-per-anchor, pos maxima in LDS,
// write all sparse fixups.
__global__ __launch_bounds__(KAT) void k_assign(
    const float* __restrict__ pd_scores, const float* __restrict__ pd_bboxes,
    const int* __restrict__ gt_labels, const float* __restrict__ gt_bboxes,
    const int4* __restrict__ sel, const int* __restrict__ sel_cnt,
    float* __restrict__ out)
{
    __shared__ unsigned s_cnt[NA];       // claim count per anchor (33.6 KB)
    __shared__ unsigned s_min[NA];       // min claiming gt per anchor (33.6 KB)
    __shared__ unsigned s_pa[NM], s_po[NM];   // pos_align / pos_overlaps (uint max)
    __shared__ int  s_mn;
    __shared__ int4 s_multi[320];        // {a, m*, align_bits, done}; cap 640/2
    int b = blockIdx.x;
    int t = threadIdx.x;

    for (int j = t; j < NA; j += KAT){ s_cnt[j] = 0u; s_min[j] = 0xffffffffu; }
    if (t < NM){ s_pa[t] = 0u; s_po[t] = 0u; }
    if (t == 0) s_mn = 0;
    __syncthreads();

    // phase 1: load this thread's claim entry (64 gts x 16 slots == 1024 threads)
    int gt = t >> 4, slotn = t & 15;
    bool has = false; int a = 0; float met = 0.f, ov = 0.f;
    if (slotn < sel_cnt[b*NM + gt]){
        int4 e = sel[((size_t)(b*NM + gt) << 4) + slotn];
        a = e.x; met = __int_as_float(e.y); ov = __int_as_float(e.z);
        has = true;
        atomicAdd(&s_cnt[a], 1u);
        atomicMin(&s_min[a], (unsigned)gt);
    }
    __syncthreads();

    // phase 2a: single-claim anchors -> pos maxima; multi-claim -> dedup'd list
    unsigned c = 0;
    if (has){
        c = s_cnt[a];
        if (c == 1u){
            atomicMax(&s_pa[gt], __float_as_uint(met));
            atomicMax(&s_po[gt], __float_as_uint(ov));
        } else if (s_min[a] == (unsigned)gt){   // exactly one entry per multi anchor
            int k = atomicAdd(&s_mn, 1);
            s_multi[k] = make_int4(a, 0, 0, 0);
        }
    }
    __syncthreads();

    // phase 2b: one wave per multi anchor; lane mm = gt mm (jnp.argmax: first max)
    int wv = t >> 6, lane = t & 63;
    for (int k = wv; k < s_mn; k += KAT/64){
        int aa = s_multi[k].x;
        float4 p = *(const float4*)&pd_bboxes[((size_t)b*NA + aa)*4]; // broadcast
        float4 g = *(const float4*)&gt_bboxes[(b*NM + lane)*4];
        float o = ciou_clip(g.x,g.y,g.z,g.w, p.x,p.y,p.z,p.w);
        float bv = o; int bi = lane;
        #pragma unroll
        for (int d = 1; d < 64; d <<= 1){
            float o2 = __shfl_xor(bv, d);
            int   i2 = __shfl_xor(bi, d);
            if (o2 > bv || (o2 == bv && i2 < bi)){ bv = o2; bi = i2; }
        }
        if (lane == bi){                 // unique winner lane
            int lab = gt_labels[b*NM + bi];
            float al = pd_scores[((size_t)b*NA + aa)*NC + lab] * bv;
            atomicMax(&s_pa[bi], __float_as_uint(al));
            atomicMax(&s_po[bi], __float_as_uint(bv));
            s_multi[k] = make_int4(aa, bi, __float_as_int(al), 1);
        }
    }
    __syncthreads();

    // phase 3: pos arrays final -> write all fg fixups
    if (has && c == 1u)
        writefix(out, b, a, gt, met, s_pa, s_po, gt_labels, gt_bboxes);
    if (t < s_mn){
        int4 mm = s_multi[t];
        writefix(out, b, mm.x, mm.y, __int_as_float(mm.z), s_pa, s_po,
                 gt_labels, gt_bboxes);
    }
}

extern "C" void kernel_launch(void* const* d_in, const int* in_sizes, int n_in,
                              void* d_out, int out_size, void* d_ws, size_t ws_size,
                              hipStream_t stream) {
    const float* pd_scores = (const float*)d_in[0];
    const float* pd_bboxes = (const float*)d_in[1];
    const int*   gt_labels = (const int*)d_in[3];
    const float* gt_bboxes = (const float*)d_in[4];
    const float* mask_gt   = (const float*)d_in[5];
    float* out = (float*)d_out;

    // workspace: dense per-gt claim lists only (~520 KB, fully written each call)
    int4* sel     = (int4*)d_ws;                 // 2048 * 16 int4
    int*  sel_cnt = (int*)(sel + (size_t)BS*NM*16);  // 2048

    k_main<<<GRID, 256, 0, stream>>>(pd_scores, pd_bboxes, gt_labels, gt_bboxes,
                                     mask_gt, sel, sel_cnt, out);
    k_assign<<<BS, KAT, 0, stream>>>(pd_scores, pd_bboxes, gt_labels, gt_bboxes,
                                     sel, sel_cnt, out);
}